// Round 8
// baseline (64.048 us; speedup 1.0000x reference)
//
#include <hip/hip_runtime.h>

#define NB   128   // images
#define NP   512   // pairs per image
#define NC   150   // foreground classes
#define ND   1024  // PATH_DIM
#define AD   64    // d-values per compute block
#define ADB  (ND / AD)        // 16 d-blocks per image

#define BGRID 2048            // broadcast blocks
#define N4    (1u << 24)      // total output float4 count (128*512*1024 floats / 4)
#define BSTEP (BGRID * 256u)  // grid-stride in f4 = 1<<19
#define BITER (N4 / BSTEP)    // 32 iterations per thread

typedef float  f4 __attribute__((ext_vector_type(4)));
typedef int    i4 __attribute__((ext_vector_type(4)));

// Kernel A (unchanged from R6): block (img, dblk) computes y[dblk*64 .. +64)
// via LDS-staged W tile, writes into row 0 of the image's output block.
__global__ __launch_bounds__(256) void compute_y_kernel(const int* __restrict__ preds,
                                                        const float* __restrict__ W,
                                                        const float* __restrict__ bias,
                                                        float* __restrict__ out) {
    __shared__ float wl[AD * NC];     // 37.5 KB tile
    __shared__ float sflag[NC];
    __shared__ float part[4][AD];

    const unsigned bid  = blockIdx.x;
    const unsigned img  = bid >> 4;
    const unsigned dblk = bid & 15;
    const unsigned t    = threadIdx.x;

    i4 c4;
    if (t < NP / 4) c4 = ((const i4*)(preds + (size_t)img * NP))[t];

    if (t < NC) sflag[t] = 0.0f;

    const f4* wsrc = (const f4*)(W + (size_t)dblk * AD * NC);
    f4* wdst = (f4*)wl;
    #pragma unroll
    for (int i = 0; i < 10; ++i) {
        unsigned g = i * 256u + t;
        if (g < (AD * NC) / 4) wdst[g] = wsrc[g];
    }
    __syncthreads();

    if (t < NP / 4) {
        sflag[c4.x - 1] = 1.0f;   // idempotent; same-value races benign
        sflag[c4.y - 1] = 1.0f;
        sflag[c4.z - 1] = 1.0f;
        sflag[c4.w - 1] = 1.0f;
    }
    __syncthreads();

    const unsigned d = t & 63;
    const unsigned q = t >> 6;
    const unsigned c0 = q * 38;
    const unsigned c1 = (q == 3) ? NC : c0 + 38;
    float acc = 0.0f;
    const float* wrow = wl + (size_t)d * NC;
    for (unsigned c = c0; c < c1; ++c) {
        acc += sflag[c] * wrow[c];
    }
    part[q][d] = acc;
    __syncthreads();

    if (t < AD) {
        const unsigned dg = dblk * AD + t;
        float y = bias[dg] + part[0][t] + part[1][t] + part[2][t] + part[3][t];
        out[(size_t)img * NP * ND + dg] = y;
    }
}

// Kernel B: GRID-STRIDE broadcast (fill's shape). Flat f4 index idx < 2^24:
//   img = idx >> 17 (512 rows * 256 f4 per image), col-in-row = idx & 255,
//   source = row 0 of img: (idx & 0xFFFE0000) | (idx & 0xFF).
// Dense rolling ~8MB write window across the whole chip -> DRAM row-buffer
// friendly (R5/R6's 2048 independent 128KB streams ran at ~5.4 TB/s).
// Row 0 rewrites itself with the identical value -- benign.
// src reads are L2-hot (128 row-0s = 512KB per XCD).
__global__ __launch_bounds__(256) void broadcast_gs(const f4* __restrict__ src,
                                                    f4* __restrict__ out) {
    const unsigned base = blockIdx.x * 256u + threadIdx.x;
    #pragma unroll 8
    for (unsigned i = 0; i < BITER; ++i) {
        const unsigned idx = base + (i << 19);                 // += BSTEP
        const unsigned s   = (idx & 0xFFFE0000u) | (idx & 0xFFu);
        out[idx] = src[s];
    }
}

extern "C" void kernel_launch(void* const* d_in, const int* in_sizes, int n_in,
                              void* d_out, int out_size, void* d_ws, size_t ws_size,
                              hipStream_t stream) {
    const int*   preds = (const int*)d_in[0];   // pair_preds [128,512] int32
    const float* W     = (const float*)d_in[1]; // [1024,150] fp32
    const float* bias  = (const float*)d_in[2]; // [1024] fp32
    float*       out   = (float*)d_out;         // [65536,1024] fp32

    compute_y_kernel<<<dim3(NB * ADB), dim3(256), 0, stream>>>(preds, W, bias, out);
    broadcast_gs<<<dim3(BGRID), dim3(256), 0, stream>>>((const f4*)out, (f4*)out);
}

// Round 9
// 55.102 us; speedup vs baseline: 1.1624x; 1.1624x over previous
//
#include <hip/hip_runtime.h>

#define NB   128   // images
#define NP   512   // pairs per image
#define NC   150   // foreground classes
#define ND   1024  // PATH_DIM
#define AD   64    // d-values per compute block
#define ADB  (ND / AD)        // 16 d-blocks per image

typedef float  f4 __attribute__((ext_vector_type(4)));
typedef int    i4 __attribute__((ext_vector_type(4)));

// Kernel A (unchanged from R6): block (img, dblk) computes y[dblk*64 .. +64)
// via LDS-staged W tile (coalesced coop load), writes into row 0 of the
// image's output block.
__global__ __launch_bounds__(256) void compute_y_kernel(const int* __restrict__ preds,
                                                        const float* __restrict__ W,
                                                        const float* __restrict__ bias,
                                                        float* __restrict__ out) {
    __shared__ float wl[AD * NC];     // 37.5 KB tile
    __shared__ float sflag[NC];
    __shared__ float part[4][AD];

    const unsigned bid  = blockIdx.x;
    const unsigned img  = bid >> 4;
    const unsigned dblk = bid & 15;
    const unsigned t    = threadIdx.x;

    i4 c4;
    if (t < NP / 4) c4 = ((const i4*)(preds + (size_t)img * NP))[t];

    if (t < NC) sflag[t] = 0.0f;

    const f4* wsrc = (const f4*)(W + (size_t)dblk * AD * NC);
    f4* wdst = (f4*)wl;
    #pragma unroll
    for (int i = 0; i < 10; ++i) {
        unsigned g = i * 256u + t;
        if (g < (AD * NC) / 4) wdst[g] = wsrc[g];
    }
    __syncthreads();

    if (t < NP / 4) {
        sflag[c4.x - 1] = 1.0f;   // idempotent; same-value races benign
        sflag[c4.y - 1] = 1.0f;
        sflag[c4.z - 1] = 1.0f;
        sflag[c4.w - 1] = 1.0f;
    }
    __syncthreads();

    const unsigned d = t & 63;
    const unsigned q = t >> 6;
    const unsigned c0 = q * 38;
    const unsigned c1 = (q == 3) ? NC : c0 + 38;
    float acc = 0.0f;
    const float* wrow = wl + (size_t)d * NC;
    for (unsigned c = c0; c < c1; ++c) {
        acc += sflag[c] * wrow[c];
    }
    part[q][d] = acc;
    __syncthreads();

    if (t < AD) {
        const unsigned dg = dblk * AD + t;
        float y = bias[dg] + part[0][t] + part[1][t] + part[2][t] + part[3][t];
        out[(size_t)img * NP * ND + dg] = y;
    }
}

// Kernel B: ONE BLOCK PER IMAGE (512... actually 128 blocks would be 1 img
// each; we use 512 blocks = 4 per CU pair -- no: grid = NB*4 = 512 blocks,
// each owns a QUARTER image = 128 rows), wait -- keep it simple:
// grid = 512 blocks, block b owns image b>>2, row-quarter b&3 (128 rows).
// Rationale: 2 blocks/CU, 8 waves/CU; one row-0 read per 512KB written
// (16x better amortization than R5's 128KB blocks); branchless: rewrites
// row 0 with identical bytes.
__global__ __launch_bounds__(256) void broadcast_img(const f4* __restrict__ src,
                                                     f4* __restrict__ out) {
    const unsigned bid  = blockIdx.x;
    const unsigned img  = bid >> 2;
    const unsigned quad = bid & 3;
    const unsigned t    = threadIdx.x;

    const size_t base = ((size_t)img << 17);        // img * 512 rows * 256 f4
    const f4 v = src[base + t];                     // row 0 (written by A)

    f4* o = out + base + ((size_t)(quad * 128) << 8) + t;
    #pragma unroll 8
    for (unsigned p = 0; p < 128; ++p) {
        o[(size_t)p << 8] = v;                      // 4KB row stride, coalesced
    }
}

extern "C" void kernel_launch(void* const* d_in, const int* in_sizes, int n_in,
                              void* d_out, int out_size, void* d_ws, size_t ws_size,
                              hipStream_t stream) {
    const int*   preds = (const int*)d_in[0];   // pair_preds [128,512] int32
    const float* W     = (const float*)d_in[1]; // [1024,150] fp32
    const float* bias  = (const float*)d_in[2]; // [1024] fp32
    float*       out   = (float*)d_out;         // [65536,1024] fp32

    compute_y_kernel<<<dim3(NB * ADB), dim3(256), 0, stream>>>(preds, W, bias, out);
    broadcast_img<<<dim3(NB * 4), dim3(256), 0, stream>>>((const f4*)out, (f4*)out);
}

// Round 10
// 52.475 us; speedup vs baseline: 1.2206x; 1.0501x over previous
//
#include <hip/hip_runtime.h>

#define NB   128   // images
#define NP   512   // pairs per image
#define NC   150   // foreground classes
#define ND   1024  // PATH_DIM

typedef float  f4 __attribute__((ext_vector_type(4)));
typedef float  f2 __attribute__((ext_vector_type(2)));
typedef int    i4 __attribute__((ext_vector_type(4)));

// Single fused kernel. grid = 128 img x 4 dslices = 512 blocks (2/CU, 8 waves/CU).
// Block (img, dblk) owns the 256-wide d-slice [dblk*256, dblk*256+256) and
// writes it for ALL 512 rows of its image.
//   1. build multi-hot flags in LDS (512 preds as 128 i4 loads)
//   2. thread t computes y[dblk*256+t]: ONE strided W-row read per thread
//      (~10 cache lines/thread at 512 blocks -- the R5-proven-cheap pattern;
//      R3/R4's disaster was 4 rows/thread x 1024 blocks)
//   3. stage the 256-float slice in LDS, reload one f4 per lane
//   4. stream: wave w stores rows w, w+4, ... -> 1KB contiguous per wave-store,
//      identical shape to the proven broadcast kernel, but with no second
//      dispatch, no kernel boundary, and no global read dependency.
__global__ __launch_bounds__(256) void labellayer_onepass(const int* __restrict__ preds,
                                                          const float* __restrict__ W,
                                                          const float* __restrict__ bias,
                                                          float* __restrict__ out) {
    __shared__ float sflag[NC];
    __shared__ float ys[256];

    const unsigned bid  = blockIdx.x;
    const unsigned img  = bid >> 2;
    const unsigned dblk = bid & 3;
    const unsigned t    = threadIdx.x;

    // issue preds load first so its latency overlaps the flag zeroing
    i4 c4;
    if (t < NP / 4) c4 = ((const i4*)(preds + (size_t)img * NP))[t];

    if (t < NC) sflag[t] = 0.0f;
    __syncthreads();

    if (t < NP / 4) {
        sflag[c4.x - 1] = 1.0f;   // idempotent; same-value races benign
        sflag[c4.y - 1] = 1.0f;
        sflag[c4.z - 1] = 1.0f;
        sflag[c4.w - 1] = 1.0f;
    }
    __syncthreads();

    // one y per thread: d = dblk*256 + t
    const unsigned d = dblk * 256u + t;
    const f2* w = (const f2*)(W + (size_t)d * NC);   // W row: 600B, 8B-aligned
    float y = bias[d];
    #pragma unroll 5
    for (int j = 0; j < NC / 2; ++j) {
        const f2 a = w[j];
        y += sflag[2 * j] * a.x + sflag[2 * j + 1] * a.y;
    }
    ys[t] = y;
    __syncthreads();

    // reload slice as one f4 per lane; wave w streams rows w, w+4, ...
    const unsigned wv = t >> 6;
    const unsigned ln = t & 63;
    const f4 v = ((const f4*)ys)[ln];                // 2-way LDS aliasing: free

    f4* o = (f4*)out + ((size_t)img << 17)           // img * 512 rows * 256 f4
                     + (size_t)dblk * 64 + ln;       // d-slice offset + lane f4
    #pragma unroll 8
    for (unsigned p = wv; p < NP; p += 4) {
        o[(size_t)p << 8] = v;                       // row stride = 256 f4 = 1KB
    }
}

extern "C" void kernel_launch(void* const* d_in, const int* in_sizes, int n_in,
                              void* d_out, int out_size, void* d_ws, size_t ws_size,
                              hipStream_t stream) {
    const int*   preds = (const int*)d_in[0];   // pair_preds [128,512] int32
    const float* W     = (const float*)d_in[1]; // [1024,150] fp32
    const float* bias  = (const float*)d_in[2]; // [1024] fp32
    float*       out   = (float*)d_out;         // [65536,1024] fp32

    labellayer_onepass<<<dim3(NB * 4), dim3(256), 0, stream>>>(preds, W, bias, out);
}

// Round 11
// 49.781 us; speedup vs baseline: 1.2866x; 1.0541x over previous
//
#include <hip/hip_runtime.h>

#define NB   128   // images
#define NP   512   // pairs per image
#define NC   150   // foreground classes
#define ND   1024  // PATH_DIM
#define AD   64    // d-values per block
#define ADB  (ND / AD)        // 16 d-blocks per image

typedef float  f4 __attribute__((ext_vector_type(4)));
typedef int    i4 __attribute__((ext_vector_type(4)));

// Fully fused, LDS-staged. grid = 128 img x 16 dblk = 2048 blocks, 256 thr.
// Block (img, dblk):
//  P1: coop f4-load of the contiguous 37.5KB W tile (coalesced; kills the
//      strided-read L1 amplification that cost R10 ~10us) + preds flags.
//  P2: 4-way class-split reduce -> y[64] in LDS (R6's proven kernel A).
//  P3: store [512 rows x 64 d] slab; thread (c=t&15, r0=t>>4) writes rows
//      r0, r0+16, ... : 16 lines/wave-store == ideal coalescing.
// 39.4KB LDS -> 4 resident blocks/CU (16 waves): later blocks' prologues
// overlap earlier blocks' store streams.
__global__ __launch_bounds__(256) void labellayer_fused2(const int* __restrict__ preds,
                                                         const float* __restrict__ W,
                                                         const float* __restrict__ bias,
                                                         float* __restrict__ out) {
    __shared__ float wl[AD * NC];     // 37.5 KB tile
    __shared__ float sflag[NC];
    __shared__ float part[4][AD];
    __shared__ float ys[AD];

    const unsigned bid  = blockIdx.x;
    const unsigned img  = bid >> 4;
    const unsigned dblk = bid & 15;
    const unsigned t    = threadIdx.x;

    // issue preds load early; latency hides under the W coop-load
    i4 c4;
    if (t < NP / 4) c4 = ((const i4*)(preds + (size_t)img * NP))[t];

    if (t < NC) sflag[t] = 0.0f;

    // cooperative W tile load: 2400 f4, contiguous, 16B-aligned
    const f4* wsrc = (const f4*)(W + (size_t)dblk * AD * NC);
    f4* wdst = (f4*)wl;
    #pragma unroll
    for (int i = 0; i < 10; ++i) {
        unsigned g = i * 256u + t;
        if (g < (AD * NC) / 4) wdst[g] = wsrc[g];
    }
    __syncthreads();   // flag zeros visible before scatter

    if (t < NP / 4) {
        sflag[c4.x - 1] = 1.0f;   // idempotent; same-value races benign
        sflag[c4.y - 1] = 1.0f;
        sflag[c4.z - 1] = 1.0f;
        sflag[c4.w - 1] = 1.0f;
    }
    __syncthreads();   // flags + W tile visible

    // P2: wave q reduces classes [q*38, min(q*38+38,150)) for d = t&63
    {
        const unsigned d  = t & 63;
        const unsigned q  = t >> 6;
        const unsigned c0 = q * 38;
        const unsigned c1 = (q == 3) ? NC : c0 + 38;
        float acc = 0.0f;
        const float* wrow = wl + (size_t)d * NC;
        for (unsigned c = c0; c < c1; ++c) {
            acc += sflag[c] * wrow[c];
        }
        part[q][d] = acc;
    }
    __syncthreads();

    if (t < AD) {
        ys[t] = bias[dblk * AD + t] + part[0][t] + part[1][t] + part[2][t] + part[3][t];
    }
    __syncthreads();

    // P3: slab store. c = f4 column (16 per 64-d slab), r0 = starting row.
    const unsigned c  = t & 15;
    const unsigned r0 = t >> 4;
    const f4 v = ((const f4*)ys)[c];

    f4* o = (f4*)out + ((size_t)img << 17)       // img * 512 rows * 256 f4
                     + ((size_t)dblk << 4) + c;  // slab column offset
    #pragma unroll 8
    for (unsigned p = r0; p < NP; p += 16) {
        o[(size_t)p << 8] = v;                   // row stride = 256 f4 = 1KB
    }
}

extern "C" void kernel_launch(void* const* d_in, const int* in_sizes, int n_in,
                              void* d_out, int out_size, void* d_ws, size_t ws_size,
                              hipStream_t stream) {
    const int*   preds = (const int*)d_in[0];   // pair_preds [128,512] int32
    const float* W     = (const float*)d_in[1]; // [1024,150] fp32
    const float* bias  = (const float*)d_in[2]; // [1024] fp32
    float*       out   = (float*)d_out;         // [65536,1024] fp32

    labellayer_fused2<<<dim3(NB * ADB), dim3(256), 0, stream>>>(preds, W, bias, out);
}

// Round 12
// 49.562 us; speedup vs baseline: 1.2923x; 1.0044x over previous
//
#include <hip/hip_runtime.h>

#define NB   128   // images
#define NP   512   // pairs per image
#define NC   150   // foreground classes
#define ND   1024  // PATH_DIM
#define AD   64    // d-values per block
#define HD   32    // half-slab d width
#define ADB  (ND / AD)        // 16 d-blocks per image

typedef float  f4 __attribute__((ext_vector_type(4)));
typedef int    i4 __attribute__((ext_vector_type(4)));

// Fused + sub-slab pipelined. grid = 128 img x 16 dblk = 2048 blocks, 256 thr.
// Per block (img, dblk), d-range [dblk*64, dblk*64+64), split in two 32-d halves:
//   load W half0 -> flags -> (issue half1 W global->reg, T14) -> reduce half0
//   -> ys0 -> STORE half0 (stores begin ~1.2us in, vs ~2.5us for monolithic)
//   -> ds_write half1 -> reduce half1 -> ys1 -> STORE half1.
// Store chunks = 8 f4 = 128B = exactly one cache line (full-line writes, no RFO).
// LDS ~40.3KB -> 4 resident blocks/CU; later blocks' prologues hide under
// earlier blocks' store streams.
__global__ __launch_bounds__(256) void labellayer_pipe(const int* __restrict__ preds,
                                                       const float* __restrict__ W,
                                                       const float* __restrict__ bias,
                                                       float* __restrict__ out) {
    __shared__ float wl[AD * NC];     // 38400 B; [0,4800)=half0 rows, [4800,9600)=half1
    __shared__ float sflag[NC];       // 600 B
    __shared__ float part[8][HD];     // 1 KB
    __shared__ float ys[2][HD];       // 256 B

    const unsigned bid  = blockIdx.x;
    const unsigned img  = bid >> 4;
    const unsigned dblk = bid & 15;
    const unsigned t    = threadIdx.x;

    // early loads: preds (t<128 covers 512 ints) and bias for ys writers
    i4 c4;
    if (t < NP / 4) c4 = ((const i4*)(preds + (size_t)img * NP))[t];
    float bv0 = 0.0f, bv1 = 0.0f;
    if (t < HD) {
        bv0 = bias[dblk * AD + t];
        bv1 = bias[dblk * AD + HD + t];
    }

    // coop load W half0: rows [dblk*64, +32) = 1200 f4 contiguous
    const f4* wsrc = (const f4*)(W + (size_t)dblk * AD * NC);
    f4* wdst = (f4*)wl;
    #pragma unroll
    for (int i = 0; i < 5; ++i) {
        unsigned g = i * 256u + t;
        if (g < 1200u) wdst[g] = wsrc[g];
    }
    if (t < NC) sflag[t] = 0.0f;
    __syncthreads();   // flag zeros + half0 writers ordered before scatter

    if (t < NP / 4) {
        sflag[c4.x - 1] = 1.0f;   // idempotent; same-value races benign
        sflag[c4.y - 1] = 1.0f;
        sflag[c4.z - 1] = 1.0f;
        sflag[c4.w - 1] = 1.0f;
    }
    // T14 async-stage: issue half1 W loads into REGS now; latency hides
    // under the barrier + reduce-0. ds_write happens after reduce-0.
    f4 h1[5];
    #pragma unroll
    for (int i = 0; i < 5; ++i) {
        unsigned g = 1200u + i * 256u + t;
        if (g < 2400u) h1[i] = wsrc[g];
    }
    __syncthreads();   // flags + wl half0 visible

    // reduce half0: class-group q = t>>5 (8 groups of 19), d = t&31
    const unsigned d  = t & 31;
    const unsigned q  = t >> 5;
    const unsigned c0 = q * 19;
    const unsigned c1 = (c0 + 19 > NC) ? NC : c0 + 19;
    {
        float acc = 0.0f;
        const float* wrow = wl + (size_t)d * NC;
        for (unsigned c = c0; c < c1; ++c) acc += sflag[c] * wrow[c];
        part[q][d] = acc;
    }
    __syncthreads();

    if (t < HD) {
        ys[0][t] = bv0 + part[0][t] + part[1][t] + part[2][t] + part[3][t]
                       + part[4][t] + part[5][t] + part[6][t] + part[7][t];
    }
    // ds_write half1 (regs staged above)
    #pragma unroll
    for (int i = 0; i < 5; ++i) {
        unsigned g = 1200u + i * 256u + t;
        if (g < 2400u) wdst[g] = h1[i];
    }
    __syncthreads();   // ys0 + wl half1 visible

    // STORE half0: 512 rows x 8 f4 (128B full-line chunks), c=t&7, r0=t>>3
    const unsigned sc = t & 7;
    const unsigned r0 = t >> 3;          // [0,32)
    {
        const f4 v0 = ((const f4*)ys[0])[sc];
        f4* o = (f4*)out + ((size_t)img << 17) + ((size_t)dblk << 4) + sc;
        #pragma unroll 8
        for (unsigned p = r0; p < NP; p += 32) {
            o[(size_t)p << 8] = v0;      // fire-and-forget; drains in background
        }
    }

    // reduce half1 (wl offset 4800 floats) while half0 stores drain
    {
        float acc = 0.0f;
        const float* wrow = wl + 4800 + (size_t)d * NC;
        for (unsigned c = c0; c < c1; ++c) acc += sflag[c] * wrow[c];
        __syncthreads();                 // part WAR: ys0 readers done (barrier above)
        part[q][d] = acc;
    }
    __syncthreads();

    if (t < HD) {
        ys[1][t] = bv1 + part[0][t] + part[1][t] + part[2][t] + part[3][t]
                       + part[4][t] + part[5][t] + part[6][t] + part[7][t];
    }
    __syncthreads();

    // STORE half1
    {
        const f4 v1 = ((const f4*)ys[1])[sc];
        f4* o = (f4*)out + ((size_t)img << 17) + ((size_t)dblk << 4) + 8 + sc;
        #pragma unroll 8
        for (unsigned p = r0; p < NP; p += 32) {
            o[(size_t)p << 8] = v1;
        }
    }
}

extern "C" void kernel_launch(void* const* d_in, const int* in_sizes, int n_in,
                              void* d_out, int out_size, void* d_ws, size_t ws_size,
                              hipStream_t stream) {
    const int*   preds = (const int*)d_in[0];   // pair_preds [128,512] int32
    const float* W     = (const float*)d_in[1]; // [1024,150] fp32
    const float* bias  = (const float*)d_in[2]; // [1024] fp32
    float*       out   = (float*)d_out;         // [65536,1024] fp32

    labellayer_pipe<<<dim3(NB * ADB), dim3(256), 0, stream>>>(preds, W, bias, out);
}